// Round 7
// baseline (480.291 us; speedup 1.0000x reference)
//
#include <hip/hip_runtime.h>
#include <hip/hip_bf16.h>

#define N_POI     10000
#define SEQ_LEN   4096
#define STATE_LEN 2048

typedef float  fx4 __attribute__((ext_vector_type(4)));   // clang vector: valid for nontemporal builtins

// One block per output row (2048 blocks, 512 threads).
// Each thread owns 8 contiguous columns: int4-vectorized history loads,
// random gathers from one 40KB P-row (L1/L2 resident), fused stable softmax,
// 2x nontemporal float4 stores (output is write-once; don't evict P rows).
__global__ __launch_bounds__(512)
void attn_softmax_gather_kernel(const int* __restrict__ history,
                                const int* __restrict__ current,
                                const float* __restrict__ P,
                                float* __restrict__ out) {
    const int row  = blockIdx.x;          // 0..STATE_LEN-1
    const int t    = threadIdx.x;         // 0..511
    const int lane = t & 63;
    const int wid  = t >> 6;              // 0..7

    const int r = current[row];           // uniform across block (scalar load)
    const float* __restrict__ prow = P + (size_t)r * N_POI;

    // 8 contiguous column indices per thread, vectorized
    const int4* h4 = (const int4*)history;
    int4 h0 = h4[t * 2];
    int4 h1 = h4[t * 2 + 1];

    float e[8];
    e[0] = 1.0f / prow[h0.x];
    e[1] = 1.0f / prow[h0.y];
    e[2] = 1.0f / prow[h0.z];
    e[3] = 1.0f / prow[h0.w];
    e[4] = 1.0f / prow[h1.x];
    e[5] = 1.0f / prow[h1.y];
    e[6] = 1.0f / prow[h1.z];
    e[7] = 1.0f / prow[h1.w];

    // ---- block max ----
    float m = fmaxf(fmaxf(fmaxf(e[0], e[1]), fmaxf(e[2], e[3])),
                    fmaxf(fmaxf(e[4], e[5]), fmaxf(e[6], e[7])));
    #pragma unroll
    for (int off = 32; off > 0; off >>= 1)
        m = fmaxf(m, __shfl_xor(m, off));

    __shared__ float red[8];
    if (lane == 0) red[wid] = m;
    __syncthreads();
    m = fmaxf(fmaxf(fmaxf(red[0], red[1]), fmaxf(red[2], red[3])),
              fmaxf(fmaxf(red[4], red[5]), fmaxf(red[6], red[7])));
    __syncthreads();   // red[] about to be reused for the sum

    // ---- exp + block sum ----
    float ex[8];
    float s = 0.0f;
    #pragma unroll
    for (int i = 0; i < 8; ++i) {
        ex[i] = expf(e[i] - m);
        s += ex[i];
    }
    #pragma unroll
    for (int off = 32; off > 0; off >>= 1)
        s += __shfl_xor(s, off);

    if (lane == 0) red[wid] = s;
    __syncthreads();
    s = (red[0] + red[1]) + (red[2] + red[3])
      + (red[4] + red[5]) + (red[6] + red[7]);

    const float inv = 1.0f / s;

    fx4 o0 = { ex[0] * inv, ex[1] * inv, ex[2] * inv, ex[3] * inv };
    fx4 o1 = { ex[4] * inv, ex[5] * inv, ex[6] * inv, ex[7] * inv };

    fx4* orow = (fx4*)(out + (size_t)row * SEQ_LEN);
    __builtin_nontemporal_store(o0, &orow[t * 2]);
    __builtin_nontemporal_store(o1, &orow[t * 2 + 1]);
}

extern "C" void kernel_launch(void* const* d_in, const int* in_sizes, int n_in,
                              void* d_out, int out_size, void* d_ws, size_t ws_size,
                              hipStream_t stream) {
    const int*   history = (const int*)d_in[0];
    const int*   current = (const int*)d_in[1];
    const float* P       = (const float*)d_in[2];
    float*       out     = (float*)d_out;

    attn_softmax_gather_kernel<<<STATE_LEN, 512, 0, stream>>>(history, current, P, out);
}

// Round 11
// 462.294 us; speedup vs baseline: 1.0389x; 1.0389x over previous
//
#include <hip/hip_runtime.h>
#include <hip/hip_bf16.h>

#define N_POI     10000
#define SEQ_LEN   4096
#define STATE_LEN 2048

typedef float fx4 __attribute__((ext_vector_type(4)));

// One block per output row (2048 blocks, 512 threads).
// Stage the block's 40KB P-row into LDS via coalesced float4 stream
// (fixes the L2/L3 transaction-bound random gather), then gather from LDS,
// fused stable softmax, nontemporal float4 stores.
// LDS = 40KB/block -> 4 blocks/CU = 32 waves/CU (full occupancy).
__global__ __launch_bounds__(512)
void attn_softmax_gather_kernel(const int* __restrict__ history,
                                const int* __restrict__ current,
                                const float* __restrict__ P,
                                float* __restrict__ out) {
    __shared__ float srow[N_POI];        // 40000 B
    __shared__ float red[8];

    const int row  = blockIdx.x;          // 0..STATE_LEN-1
    const int t    = threadIdx.x;         // 0..511
    const int lane = t & 63;
    const int wid  = t >> 6;              // 0..7

    const int r = current[row];           // uniform across block

    // history indices issued early (L2-hot: 16KB shared by all blocks)
    const int4* h4 = (const int4*)history;
    int4 h0 = h4[t * 2];
    int4 h1 = h4[t * 2 + 1];

    // ---- stage P row into LDS, coalesced float4 (2500 vec4 = 40KB) ----
    const fx4* __restrict__ prow4 = (const fx4*)(P + (size_t)r * N_POI);
    fx4* s4 = (fx4*)srow;
    for (int i = t; i < N_POI / 4; i += 512)
        s4[i] = prow4[i];
    __syncthreads();

    // ---- gather from LDS + fast rcp ----
    float e[8];
    e[0] = __builtin_amdgcn_rcpf(srow[h0.x]);
    e[1] = __builtin_amdgcn_rcpf(srow[h0.y]);
    e[2] = __builtin_amdgcn_rcpf(srow[h0.z]);
    e[3] = __builtin_amdgcn_rcpf(srow[h0.w]);
    e[4] = __builtin_amdgcn_rcpf(srow[h1.x]);
    e[5] = __builtin_amdgcn_rcpf(srow[h1.y]);
    e[6] = __builtin_amdgcn_rcpf(srow[h1.z]);
    e[7] = __builtin_amdgcn_rcpf(srow[h1.w]);

    // ---- block max ----
    float m = fmaxf(fmaxf(fmaxf(e[0], e[1]), fmaxf(e[2], e[3])),
                    fmaxf(fmaxf(e[4], e[5]), fmaxf(e[6], e[7])));
    #pragma unroll
    for (int off = 32; off > 0; off >>= 1)
        m = fmaxf(m, __shfl_xor(m, off));

    if (lane == 0) red[wid] = m;
    __syncthreads();
    m = fmaxf(fmaxf(fmaxf(red[0], red[1]), fmaxf(red[2], red[3])),
              fmaxf(fmaxf(red[4], red[5]), fmaxf(red[6], red[7])));
    __syncthreads();   // red[] about to be reused for the sum

    // ---- exp + block sum ----
    float ex[8];
    float s = 0.0f;
    #pragma unroll
    for (int i = 0; i < 8; ++i) {
        ex[i] = __expf(e[i] - m);
        s += ex[i];
    }
    #pragma unroll
    for (int off = 32; off > 0; off >>= 1)
        s += __shfl_xor(s, off);

    if (lane == 0) red[wid] = s;
    __syncthreads();
    s = (red[0] + red[1]) + (red[2] + red[3])
      + (red[4] + red[5]) + (red[6] + red[7]);

    const float inv = __builtin_amdgcn_rcpf(s);

    fx4 o0 = { ex[0] * inv, ex[1] * inv, ex[2] * inv, ex[3] * inv };
    fx4 o1 = { ex[4] * inv, ex[5] * inv, ex[6] * inv, ex[7] * inv };

    fx4* orow = (fx4*)(out + (size_t)row * SEQ_LEN);
    __builtin_nontemporal_store(o0, &orow[t * 2]);
    __builtin_nontemporal_store(o1, &orow[t * 2 + 1]);
}

extern "C" void kernel_launch(void* const* d_in, const int* in_sizes, int n_in,
                              void* d_out, int out_size, void* d_ws, size_t ws_size,
                              hipStream_t stream) {
    const int*   history = (const int*)d_in[0];
    const int*   current = (const int*)d_in[1];
    const float* P       = (const float*)d_in[2];
    float*       out     = (float*)d_out;

    attn_softmax_gather_kernel<<<STATE_LEN, 512, 0, stream>>>(history, current, P, out);
}

// Round 14
// 461.763 us; speedup vs baseline: 1.0401x; 1.0011x over previous
//
#include <hip/hip_runtime.h>
#include <hip/hip_bf16.h>

#define N_POI     10000
#define SEQ_LEN   4096
#define STATE_LEN 2048

typedef float fx4 __attribute__((ext_vector_type(4)));

// One block per output row (2048 blocks, 512 threads).
// Stage the block's 40KB P-row into LDS (register-staged, all 5 global loads
// in flight), gather from LDS, fused stable softmax (3 barriers), fast
// rcp/exp intrinsics, nontemporal float4 stores.
// LDS = 40KB/block -> 4 blocks/CU, 32 waves/CU.
__global__ __launch_bounds__(512)
void attn_softmax_gather_kernel(const int* __restrict__ history,
                                const int* __restrict__ current,
                                const float* __restrict__ P,
                                float* __restrict__ out) {
    __shared__ float srow[N_POI];        // 40000 B
    __shared__ float redm[8];
    __shared__ float reds[8];

    const int row  = blockIdx.x;          // 0..STATE_LEN-1
    const int t    = threadIdx.x;         // 0..511
    const int lane = t & 63;
    const int wid  = t >> 6;              // 0..7

    const int r = current[row];           // uniform across block

    // history indices issued early (L2-hot: shared by all blocks)
    const int4* h4 = (const int4*)history;
    int4 h0 = h4[t * 2];
    int4 h1 = h4[t * 2 + 1];

    // ---- stage P row into LDS: 2500 float4 = 40KB, 5 loads in flight ----
    const fx4* __restrict__ prow4 = (const fx4*)(P + (size_t)r * N_POI);
    fx4* s4 = (fx4*)srow;
    fx4 v0 = prow4[t];
    fx4 v1 = prow4[t + 512];
    fx4 v2 = prow4[t + 1024];
    fx4 v3 = prow4[t + 1536];
    fx4 v4 = {0.f, 0.f, 0.f, 0.f};
    if (t < 452) v4 = prow4[t + 2048];    // 2500 - 2048 = 452
    s4[t]        = v0;
    s4[t + 512]  = v1;
    s4[t + 1024] = v2;
    s4[t + 1536] = v3;
    if (t < 452) s4[t + 2048] = v4;
    __syncthreads();

    // ---- gather from LDS + fast rcp ----
    float e[8];
    e[0] = __builtin_amdgcn_rcpf(srow[h0.x]);
    e[1] = __builtin_amdgcn_rcpf(srow[h0.y]);
    e[2] = __builtin_amdgcn_rcpf(srow[h0.z]);
    e[3] = __builtin_amdgcn_rcpf(srow[h0.w]);
    e[4] = __builtin_amdgcn_rcpf(srow[h1.x]);
    e[5] = __builtin_amdgcn_rcpf(srow[h1.y]);
    e[6] = __builtin_amdgcn_rcpf(srow[h1.z]);
    e[7] = __builtin_amdgcn_rcpf(srow[h1.w]);

    // ---- block max ----
    float m = fmaxf(fmaxf(fmaxf(e[0], e[1]), fmaxf(e[2], e[3])),
                    fmaxf(fmaxf(e[4], e[5]), fmaxf(e[6], e[7])));
    #pragma unroll
    for (int off = 32; off > 0; off >>= 1)
        m = fmaxf(m, __shfl_xor(m, off));

    if (lane == 0) redm[wid] = m;
    __syncthreads();
    m = fmaxf(fmaxf(fmaxf(redm[0], redm[1]), fmaxf(redm[2], redm[3])),
              fmaxf(fmaxf(redm[4], redm[5]), fmaxf(redm[6], redm[7])));

    // ---- exp + block sum (separate buffer: no barrier needed before write) ----
    float ex[8];
    float s = 0.0f;
    #pragma unroll
    for (int i = 0; i < 8; ++i) {
        ex[i] = __expf(e[i] - m);
        s += ex[i];
    }
    #pragma unroll
    for (int off = 32; off > 0; off >>= 1)
        s += __shfl_xor(s, off);

    if (lane == 0) reds[wid] = s;
    __syncthreads();
    s = (reds[0] + reds[1]) + (reds[2] + reds[3])
      + (reds[4] + reds[5]) + (reds[6] + reds[7]);

    const float inv = __builtin_amdgcn_rcpf(s);

    fx4 o0 = { ex[0] * inv, ex[1] * inv, ex[2] * inv, ex[3] * inv };
    fx4 o1 = { ex[4] * inv, ex[5] * inv, ex[6] * inv, ex[7] * inv };

    fx4* orow = (fx4*)(out + (size_t)row * SEQ_LEN);
    __builtin_nontemporal_store(o0, &orow[t * 2]);
    __builtin_nontemporal_store(o1, &orow[t * 2 + 1]);
}

extern "C" void kernel_launch(void* const* d_in, const int* in_sizes, int n_in,
                              void* d_out, int out_size, void* d_ws, size_t ws_size,
                              hipStream_t stream) {
    const int*   history = (const int*)d_in[0];
    const int*   current = (const int*)d_in[1];
    const float* P       = (const float*)d_in[2];
    float*       out     = (float*)d_out;

    attn_softmax_gather_kernel<<<STATE_LEN, 512, 0, stream>>>(history, current, P, out);
}